// Round 9
// baseline (191.978 us; speedup 1.0000x reference)
//
#include <hip/hip_runtime.h>
#include <math.h>

#define N3 262144           // 64^3

// ===========================================================================
// Derived-feature formulation (verified R4-R8): 7-point stencil; per input row
// conv depends only on c (center), S (sum of 6 faces), D_A (axis diffs).
// Lessons:
//  - R5: acc[] indices must be compile-time constants (else scratch demotion).
//  - R6: don't fully unroll row loops (live set > 256 VGPR -> spill).
//  - R8: don't batch loads via unroll either (VGPR 128 -> occupancy loss).
//  - R9 (this): conv2 stages y tiles in LDS with float4 loads (42 wide loads
//    per thread vs 280 scalar); stencil taps read LDS.
// ===========================================================================

// Table layout (floats):
// conv1 (448): T1c[8][24]@0, T1f[8][24]@192, T1v[8][8]@384
// conv2 (1280)@448: T2c[16][24]@+0, T2f[16][24]@+384, T2sv[16][8]@+768,
//   T2vs[8][24]@+896, T2v0c[8][8]@+1088, T2v0f[8][8]@+1152, T2v1[8][8]@+1216
#define TBL_TOTAL 1728

__device__ inline void lattice_emb(int p, float* embr) {
    int i = p / 9, j = (p / 3) % 3, k = p % 3;
    float gx = (float)(i - 1), gy = (float)(j - 1), gz = (float)(k - 1);
    float r = sqrtf(gx * gx + gy * gy + gz * gz);
    const float centers[4] = {0.f, 0.33333334f, 0.6666667f, 1.f};
    const float step = 0.33333334f;
    #pragma unroll
    for (int b = 0; b < 4; b++) {
        float dd = (r - centers[b]) / step;
        float e = 0.f;
        if (fabsf(dd) < 1.f)
            e = 1.14136f * expf(2.f) * expf(-1.f / fmaxf(1.f - dd * dd, 1e-9f));
        embr[b] = e;
    }
}

// ---------------------------------------------------------------------------
// Build the derived feature matrices (1728 floats).
// ---------------------------------------------------------------------------
__global__ __launch_bounds__(256) void build_tables_kernel(
        const float* __restrict__ w1,  const float* __restrict__ sc1,
        const float* __restrict__ w2,  const float* __restrict__ sc2s,
        const float* __restrict__ sc2v, float* __restrict__ T) {
    int gid = blockIdx.x * 256 + threadIdx.x;
    if (gid >= TBL_TOTAL) return;

    const float inv_ks15 = 0.19245008972987526f;  // 1/3^1.5
    const float s3   = 1.7320508075688772f;
    const float a1   = 0.35355339059327373f;  // 1/sqrt(8)
    const float a_s  = 0.2041241452319315f;   // 1/sqrt(24)
    const float a_v  = 0.17677669529663687f;  // 1/sqrt(32)
    const float a_s3 = 0.11785113019775793f;  // a_s/sqrt(3)
    const float a_v6 = 0.07216878364870322f;  // a_v/sqrt(6)

    float embC[4], embF[4];
    lattice_emb(13, embC);   // center (r=0)
    lattice_emb(22, embF);   // face   (r=1), shared by all 6 faces

    auto WC1 = [&](int c) { float s=0.f;
        #pragma unroll
        for (int b=0;b<4;b++) s += embC[b]*w1[b*256+c]; return s*inv_ks15; };
    auto WF1 = [&](int c) { float s=0.f;
        #pragma unroll
        for (int b=0;b<4;b++) s += embF[b]*w1[b*256+c]; return s*inv_ks15; };
    auto WC2 = [&](int c) { float s=0.f;
        #pragma unroll
        for (int b=0;b<4;b++) s += embC[b]*w2[b*832+c]; return s*inv_ks15; };
    auto WF2 = [&](int c) { float s=0.f;
        #pragma unroll
        for (int b=0;b<4;b++) s += embF[b]*w2[b*832+c]; return s*inv_ks15; };

    float val = 0.f;
    if (gid < 192) {                       // T1c
        int i = gid / 24, o = gid % 24;
        int c = (o < 16) ? i * 16 + o : 128 + i * 8 + (o - 16);
        val = a1 * WC1(c) + a1 * sc1[i * 24 + o];
    } else if (gid < 384) {                // T1f
        int r = gid - 192; int i = r / 24, o = r % 24;
        int c = (o < 16) ? i * 16 + o : 128 + i * 8 + (o - 16);
        val = a1 * WF1(c);
    } else if (gid < 448) {                // T1v
        int r = gid - 384; int i = r / 8, jj = r % 8;
        val = a1 * s3 * WF1(192 + i * 8 + jj);
    } else if (gid < 832) {                // T2c
        int r = gid - 448; int i = r / 24, o = r % 24;
        int c = (o < 16) ? i * 16 + o : 256 + i * 8 + (o - 16);
        val = a_s * WC2(c) + 0.25f * sc2s[i * 24 + o];
    } else if (gid < 1216) {               // T2f
        int r = gid - 832; int i = r / 24, o = r % 24;
        int c = (o < 16) ? i * 16 + o : 256 + i * 8 + (o - 16);
        val = a_s * WF2(c);
    } else if (gid < 1344) {               // T2sv
        int r = gid - 1216; int i = r / 8, jj = r % 8;
        val = a_v * s3 * WF2(384 + i * 8 + jj);
    } else if (gid < 1536) {               // T2vs
        int r = gid - 1344; int u = r / 24, o = r % 24;
        int c = (o < 16) ? 576 + u * 16 + o : 704 + u * 8 + (o - 16);
        val = a_s3 * s3 * WF2(c);
    } else if (gid < 1600) {               // T2v0c
        int r = gid - 1536; int u = r / 8, jj = r % 8;
        val = a_v * WC2(512 + u * 8 + jj) + a1 * sc2v[u * 8 + jj];
    } else if (gid < 1664) {               // T2v0f
        int r = gid - 1600; int u = r / 8, jj = r % 8;
        val = a_v * WF2(512 + u * 8 + jj);
    } else {                               // T2v1
        int r = gid - 1664; int u = r / 8, jj = r % 8;
        val = a_v6 * s3 * WF2(768 + u * 8 + jj);
    }
    T[gid] = val;
}

// Stencil feature loader (global, for conv1): c, S, axis diffs.
#define LOADFEAT(PTR, C_, S_, DD_, DH_, DW_)                                  \
    {                                                                         \
        const float* bp = (PTR);                                              \
        float cc  = bp[0];                                                    \
        float vdm = dmok ? bp[-4096] : 0.f;                                   \
        float vdp = dpok ? bp[ 4096] : 0.f;                                   \
        float vhm = hmok ? bp[  -64] : 0.f;                                   \
        float vhp = hpok ? bp[   64] : 0.f;                                   \
        float vwm = wmok ? bp[   -1] : 0.f;                                   \
        float vwp = wpok ? bp[    1] : 0.f;                                   \
        C_ = cc;                                                              \
        S_ = vdm + vdp + vhm + vhp + vwm + vwp;                               \
        DD_ = vdp - vdm; DH_ = vhp - vhm; DW_ = vwp - vwm;                    \
    }

// ---------------------------------------------------------------------------
// conv1: x(8,64^3) -> ypre(48,64^3). Derived features, fused BN stats.
// (8 channels only — direct loads, known-good unroll-1 config)
// ---------------------------------------------------------------------------
__global__ __launch_bounds__(256) void conv1_kernel(const float* __restrict__ x,
                                                    const float* __restrict__ Tg,
                                                    float* __restrict__ out,
                                                    float* __restrict__ stats) {
    __shared__ float T[448];
    __shared__ float red[4][72];
    for (int t = threadIdx.x; t < 448; t += 256) T[t] = Tg[t];
    __syncthreads();

    int idx = blockIdx.x * 256 + threadIdx.x;
    int w = idx & 63, h = (idx >> 6) & 63, d = idx >> 12;
    bool dmok = d > 0, dpok = d < 63, hmok = h > 0, hpok = h < 63,
         wmok = w > 0, wpok = w < 63;

    float acc[48];
    #pragma unroll
    for (int o = 0; o < 48; o++) acc[o] = 0.f;

    #pragma unroll 1
    for (int i = 0; i < 8; i++) {
        float c, S, Dd, Dh, Dw;
        LOADFEAT(x + i * N3 + idx, c, S, Dd, Dh, Dw);
        const float* tc = &T[i * 24];
        const float* tf = &T[192 + i * 24];
        #pragma unroll
        for (int o = 0; o < 24; o++) acc[o] += tc[o] * c + tf[o] * S;
        const float* tv = &T[384 + i * 8];
        #pragma unroll
        for (int jj = 0; jj < 8; jj++) {
            float wv = tv[jj];
            acc[24 + jj * 3 + 0] += wv * Dd;
            acc[24 + jj * 3 + 1] += wv * Dh;
            acc[24 + jj * 3 + 2] += wv * Dw;
        }
    }
    #pragma unroll
    for (int o = 0; o < 48; o++) out[o * N3 + idx] = acc[o];

    // fused BN partial stats: q<24 -> sum(ch q); q in [24,72) -> sumsq(ch q-24)
    int lane = threadIdx.x & 63, wv = threadIdx.x >> 6;
    #pragma unroll
    for (int q = 0; q < 72; q++) {
        float val = (q < 24) ? acc[q] : acc[q - 24] * acc[q - 24];
        #pragma unroll
        for (int m = 32; m >= 1; m >>= 1) val += __shfl_xor(val, m, 64);
        if (lane == 0) red[wv][q] = val;
    }
    __syncthreads();
    if (threadIdx.x < 72) {
        float s = red[0][threadIdx.x] + red[1][threadIdx.x] +
                  red[2][threadIdx.x] + red[3][threadIdx.x];
        atomicAdd(&stats[threadIdx.x], s);
    }
}

// ---------------------------------------------------------------------------
// conv2: y(40,64^3) -> zpre(48,64^3). LDS-staged tiles.
// Block = 4 h-rows x 64 w at one d. Tile rows per channel (stride 72, data
// at col 4..67, zeros at col 3/68):
//   rows 0..5  = (d,   h0-1 .. h0+4)
//   rows 6..9  = (d-1, h0   .. h0+3)
//   rows 10..13= (d+1, h0   .. h0+3)
// Channel groups: 2x8 scalar rows, then 4x(2u -> 6 vector rows).
// ---------------------------------------------------------------------------
__global__ __launch_bounds__(256) void conv2_kernel(const float* __restrict__ y,
                                                    const float* __restrict__ Tg,
                                                    float* __restrict__ out,
                                                    float* __restrict__ stats) {
    __shared__ float T[1280];
    __shared__ float L[8 * 14 * 72];   // 32.25 KB
    __shared__ float red[4][72];
    for (int t = threadIdx.x; t < 1280; t += 256) T[t] = Tg[448 + t];

    int bid = blockIdx.x;
    int d = bid >> 4, h0 = (bid & 15) << 2;
    int tid = threadIdx.x;
    int hr = tid >> 6, w = tid & 63;
    int idx = (d << 12) + ((h0 + hr) << 6) + w;

    float acc[48];
    #pragma unroll
    for (int o = 0; o < 48; o++) acc[o] = 0.f;

    const int off_c = (1 + hr) * 72 + 4 + w;

    #pragma unroll 1
    for (int g = 0; g < 6; g++) {
        const int gch  = (g < 2) ? 8 : 6;
        const int base = (g < 2) ? g * 8 : 16 + (g - 2) * 6;

        __syncthreads();   // WAR: previous group's reads done before overwrite
        // ---- stage (float4, coalesced) ----
        int nf4 = gch * 224;  // 14 rows * 16 quads per channel
        for (int f = tid; f < nf4; f += 256) {
            int ch = f / 224, rem = f % 224;
            int row = rem / 16, wq = (rem % 16) * 4;
            int dd = d, hh;
            if (row < 6)       { hh = h0 - 1 + row; }
            else if (row < 10) { hh = h0 + row - 6;  dd = d - 1; }
            else               { hh = h0 + row - 10; dd = d + 1; }
            float4 v = make_float4(0.f, 0.f, 0.f, 0.f);
            if ((unsigned)hh < 64u && (unsigned)dd < 64u)
                v = *(const float4*)(y + (base + ch) * N3 + (dd << 12) + (hh << 6) + wq);
            *(float4*)&L[(ch * 14 + row) * 72 + 4 + wq] = v;
        }
        if (tid < gch * 28) {   // zero pads (cols 3 and 68)
            int ch = tid / 28, r2 = tid % 28;
            int row = r2 >> 1, side = r2 & 1;
            L[(ch * 14 + row) * 72 + (side ? 68 : 3)] = 0.f;
        }
        __syncthreads();

        // ---- compute from LDS ----
        if (g < 2) {
            #pragma unroll 1
            for (int ci = 0; ci < 8; ci++) {
                const float* Lc = &L[ci * 1008];
                float c  = Lc[off_c];
                float hm = Lc[off_c - 72], hp = Lc[off_c + 72];
                float wm = Lc[off_c - 1],  wp = Lc[off_c + 1];
                float dm = Lc[off_c + 5 * 72], dp = Lc[off_c + 9 * 72];
                float S  = hm + hp + wm + wp + dm + dp;
                float Dd = dp - dm, Dh = hp - hm, Dw = wp - wm;
                int i = base + ci;
                const float* tc = &T[i * 24];
                const float* tf = &T[384 + i * 24];
                #pragma unroll
                for (int o = 0; o < 24; o++) acc[o] += tc[o] * c + tf[o] * S;
                const float* tv = &T[768 + i * 8];
                #pragma unroll
                for (int jj = 0; jj < 8; jj++) {
                    float wv = tv[jj];
                    acc[24 + jj * 3 + 0] += wv * Dd;
                    acc[24 + jj * 3 + 1] += wv * Dh;
                    acc[24 + jj * 3 + 2] += wv * Dw;
                }
            }
        } else {
            #pragma unroll 1
            for (int ul = 0; ul < 2; ul++) {
                int u = (g - 2) * 2 + ul;
                float c0, S0, D0_0, D0_1, D0_2;
                float c1, S1, D1_0, D1_1, D1_2;
                float c2, S2, D2_0, D2_1, D2_2;
                {
                    const float* Lc = &L[(ul * 3 + 0) * 1008];
                    float c = Lc[off_c], hm = Lc[off_c - 72], hp = Lc[off_c + 72],
                          wm = Lc[off_c - 1], wp = Lc[off_c + 1],
                          dm = Lc[off_c + 5 * 72], dp = Lc[off_c + 9 * 72];
                    c0 = c; S0 = hm + hp + wm + wp + dm + dp;
                    D0_0 = dp - dm; D0_1 = hp - hm; D0_2 = wp - wm;
                }
                {
                    const float* Lc = &L[(ul * 3 + 1) * 1008];
                    float c = Lc[off_c], hm = Lc[off_c - 72], hp = Lc[off_c + 72],
                          wm = Lc[off_c - 1], wp = Lc[off_c + 1],
                          dm = Lc[off_c + 5 * 72], dp = Lc[off_c + 9 * 72];
                    c1 = c; S1 = hm + hp + wm + wp + dm + dp;
                    D1_0 = dp - dm; D1_1 = hp - hm; D1_2 = wp - wm;
                }
                {
                    const float* Lc = &L[(ul * 3 + 2) * 1008];
                    float c = Lc[off_c], hm = Lc[off_c - 72], hp = Lc[off_c + 72],
                          wm = Lc[off_c - 1], wp = Lc[off_c + 1],
                          dm = Lc[off_c + 5 * 72], dp = Lc[off_c + 9 * 72];
                    c2 = c; S2 = hm + hp + wm + wp + dm + dp;
                    D2_0 = dp - dm; D2_1 = hp - hm; D2_2 = wp - wm;
                }

                float Dsum = D0_0 + D1_1 + D2_2;
                const float* tvs = &T[896 + u * 24];
                #pragma unroll
                for (int o = 0; o < 24; o++) acc[o] += tvs[o] * Dsum;

                const float* t0c = &T[1088 + u * 8];
                const float* t0f = &T[1152 + u * 8];
                const float* tv1 = &T[1216 + u * 8];
                #pragma unroll
                for (int jj = 0; jj < 8; jj++) {
                    float kc = t0c[jj], kf = t0f[jj], k1 = tv1[jj];
                    float a0 = acc[24 + jj * 3 + 0];
                    float a1 = acc[24 + jj * 3 + 1];
                    float a2 = acc[24 + jj * 3 + 2];
                    a0 += kc * c0 + kf * S0;          // m=0 vv0
                    a2 += k1 * D0_1; a1 -= k1 * D0_2; // m=0 vv1
                    a1 += kc * c1 + kf * S1;          // m=1 vv0
                    a0 += k1 * D1_2; a2 -= k1 * D1_0; // m=1 vv1
                    a2 += kc * c2 + kf * S2;          // m=2 vv0
                    a1 += k1 * D2_0; a0 -= k1 * D2_1; // m=2 vv1
                    acc[24 + jj * 3 + 0] = a0;
                    acc[24 + jj * 3 + 1] = a1;
                    acc[24 + jj * 3 + 2] = a2;
                }
            }
        }
    }

    #pragma unroll
    for (int o = 0; o < 48; o++) out[o * N3 + idx] = acc[o];

    // fused BN partial stats
    int lane = threadIdx.x & 63, wv = threadIdx.x >> 6;
    #pragma unroll
    for (int q = 0; q < 72; q++) {
        float val = (q < 24) ? acc[q] : acc[q - 24] * acc[q - 24];
        #pragma unroll
        for (int mm = 32; mm >= 1; mm >>= 1) val += __shfl_xor(val, mm, 64);
        if (lane == 0) red[wv][q] = val;
    }
    __syncthreads();
    if (threadIdx.x < 72) {
        float s = red[0][threadIdx.x] + red[1][threadIdx.x] +
                  red[2][threadIdx.x] + red[3][threadIdx.x];
        atomicAdd(&stats[threadIdx.x], s);
    }
}

// ---------------------------------------------------------------------------
// BN apply + gate (finalize inlined): zp(48ch) -> out(40ch), float4/thread
// ---------------------------------------------------------------------------
__global__ __launch_bounds__(256) void bn_gate_kernel(const float* __restrict__ zp,
                                                      const float* __restrict__ stats,
                                                      const float* __restrict__ wsc,
                                                      const float* __restrict__ bsc,
                                                      const float* __restrict__ wvc,
                                                      float* __restrict__ out) {
    __shared__ float sb[56];
    if (threadIdx.x < 32) {
        int t = threadIdx.x;
        const float invN = 1.0f / 262144.0f;
        if (t < 24) {
            float mu = stats[t] * invN;
            float var = stats[24 + t] * invN - mu * mu;
            float inv = rsqrtf(var + 1e-5f);
            sb[t] = wsc[t] * inv;
            sb[24 + t] = bsc[t] - mu * wsc[t] * inv;
        } else {
            int u = t - 24;
            float s2 = stats[48 + u * 3] + stats[48 + u * 3 + 1] + stats[48 + u * 3 + 2];
            sb[48 + u] = wvc[u] * rsqrtf(s2 * invN + 1e-5f);
        }
    }
    __syncthreads();

    int idx = (blockIdx.x * 256 + threadIdx.x) * 4;
    float4 g[8];
    #pragma unroll
    for (int u = 0; u < 8; u++) {
        float4 v = *(const float4*)(zp + (16 + u) * N3 + idx);
        float sc = sb[16 + u], bi = sb[40 + u];
        g[u].x = 1.0f / (1.0f + expf(-(v.x * sc + bi)));
        g[u].y = 1.0f / (1.0f + expf(-(v.y * sc + bi)));
        g[u].z = 1.0f / (1.0f + expf(-(v.z * sc + bi)));
        g[u].w = 1.0f / (1.0f + expf(-(v.w * sc + bi)));
    }
    #pragma unroll
    for (int c = 0; c < 16; c++) {
        float4 v = *(const float4*)(zp + c * N3 + idx);
        float sc = sb[c], bi = sb[24 + c];
        float4 r;
        r.x = fmaxf(v.x * sc + bi, 0.f);
        r.y = fmaxf(v.y * sc + bi, 0.f);
        r.z = fmaxf(v.z * sc + bi, 0.f);
        r.w = fmaxf(v.w * sc + bi, 0.f);
        *(float4*)(out + c * N3 + idx) = r;
    }
    #pragma unroll
    for (int u = 0; u < 8; u++) {
        float sv = sb[48 + u];
        #pragma unroll
        for (int m = 0; m < 3; m++) {
            float4 v = *(const float4*)(zp + (24 + u * 3 + m) * N3 + idx);
            float4 r;
            r.x = v.x * sv * g[u].x;
            r.y = v.y * sv * g[u].y;
            r.z = v.z * sv * g[u].z;
            r.w = v.w * sv * g[u].w;
            *(float4*)(out + (16 + u * 3 + m) * N3 + idx) = r;
        }
    }
}

// ---------------------------------------------------------------------------
extern "C" void kernel_launch(void* const* d_in, const int* in_sizes, int n_in,
                              void* d_out, int out_size, void* d_ws, size_t ws_size,
                              hipStream_t stream) {
    const float* x      = (const float*)d_in[0];
    const float* w1     = (const float*)d_in[1];
    const float* sc1    = (const float*)d_in[2];
    const float* w2     = (const float*)d_in[3];
    const float* sc2s   = (const float*)d_in[4];
    const float* sc2v   = (const float*)d_in[5];
    const float* bn1_ws = (const float*)d_in[6];
    const float* bn1_bs = (const float*)d_in[7];
    const float* bn1_wv = (const float*)d_in[8];
    const float* bn2_ws = (const float*)d_in[9];
    const float* bn2_bs = (const float*)d_in[10];
    const float* bn2_wv = (const float*)d_in[11];
    float* out = (float*)d_out;
    char* ws = (char*)d_ws;

    float* Tg     = (float*)(ws + 0);        // 1728 floats = 6912 B
    float* stats1 = (float*)(ws + 8192);     // 72 floats
    float* stats2 = (float*)(ws + 8192 + 512);
    float* bufA   = (float*)(ws + 262144);   // 48*N3*4 = 50331648 B

    hipMemsetAsync(ws + 8192, 0, 1024, stream);
    hipLaunchKernelGGL(build_tables_kernel, dim3(7), dim3(256), 0, stream,
                       w1, sc1, w2, sc2s, sc2v, Tg);
    hipLaunchKernelGGL(conv1_kernel, dim3(1024), dim3(256), 0, stream, x, Tg, bufA, stats1);
    hipLaunchKernelGGL(bn_gate_kernel, dim3(256), dim3(256), 0, stream,
                       bufA, stats1, bn1_ws, bn1_bs, bn1_wv, out);
    hipLaunchKernelGGL(conv2_kernel, dim3(1024), dim3(256), 0, stream, out, Tg, bufA, stats2);
    hipLaunchKernelGGL(bn_gate_kernel, dim3(256), dim3(256), 0, stream,
                       bufA, stats2, bn2_ws, bn2_bs, bn2_wv, out);
}

// Round 10
// 157.833 us; speedup vs baseline: 1.2163x; 1.2163x over previous
//
#include <hip/hip_runtime.h>
#include <math.h>

#define N3 262144           // 64^3

// ===========================================================================
// Derived-feature formulation (verified R4-R9): 7-point stencil; per input row
// conv depends only on c (center), S (sum of 6 faces), D_A (axis diffs).
// Lessons:
//  - R5: acc[] indices must be compile-time constants (else scratch demotion).
//  - R6: don't fully unroll row loops (live set > 256 VGPR -> spill).
//  - R8: compiler unroll batches loads then drains vmcnt -> no overlap.
//  - R9: LDS staging loses (syncs + bank conflicts + LDS occupancy cost).
//  - R10 (this): wave == w-row, so w+-1 taps come from __shfl (removes 2/7
//    loads); manual depth-1 prefetch overlaps row i+1 loads with row i FMAs.
// ===========================================================================

// Table layout (floats):
// conv1 (448): T1c[8][24]@0, T1f[8][24]@192, T1v[8][8]@384
// conv2 (1280)@448: T2c[16][24]@+0, T2f[16][24]@+384, T2sv[16][8]@+768,
//   T2vs[8][24]@+896, T2v0c[8][8]@+1088, T2v0f[8][8]@+1152, T2v1[8][8]@+1216
#define TBL_TOTAL 1728

__device__ inline void lattice_emb(int p, float* embr) {
    int i = p / 9, j = (p / 3) % 3, k = p % 3;
    float gx = (float)(i - 1), gy = (float)(j - 1), gz = (float)(k - 1);
    float r = sqrtf(gx * gx + gy * gy + gz * gz);
    const float centers[4] = {0.f, 0.33333334f, 0.6666667f, 1.f};
    const float step = 0.33333334f;
    #pragma unroll
    for (int b = 0; b < 4; b++) {
        float dd = (r - centers[b]) / step;
        float e = 0.f;
        if (fabsf(dd) < 1.f)
            e = 1.14136f * expf(2.f) * expf(-1.f / fmaxf(1.f - dd * dd, 1e-9f));
        embr[b] = e;
    }
}

// ---------------------------------------------------------------------------
// Build the derived feature matrices (1728 floats).
// ---------------------------------------------------------------------------
__global__ __launch_bounds__(256) void build_tables_kernel(
        const float* __restrict__ w1,  const float* __restrict__ sc1,
        const float* __restrict__ w2,  const float* __restrict__ sc2s,
        const float* __restrict__ sc2v, float* __restrict__ T) {
    int gid = blockIdx.x * 256 + threadIdx.x;
    if (gid >= TBL_TOTAL) return;

    const float inv_ks15 = 0.19245008972987526f;  // 1/3^1.5
    const float s3   = 1.7320508075688772f;
    const float a1   = 0.35355339059327373f;  // 1/sqrt(8)
    const float a_s  = 0.2041241452319315f;   // 1/sqrt(24)
    const float a_v  = 0.17677669529663687f;  // 1/sqrt(32)
    const float a_s3 = 0.11785113019775793f;  // a_s/sqrt(3)
    const float a_v6 = 0.07216878364870322f;  // a_v/sqrt(6)

    float embC[4], embF[4];
    lattice_emb(13, embC);   // center (r=0)
    lattice_emb(22, embF);   // face   (r=1), shared by all 6 faces

    auto WC1 = [&](int c) { float s=0.f;
        #pragma unroll
        for (int b=0;b<4;b++) s += embC[b]*w1[b*256+c]; return s*inv_ks15; };
    auto WF1 = [&](int c) { float s=0.f;
        #pragma unroll
        for (int b=0;b<4;b++) s += embF[b]*w1[b*256+c]; return s*inv_ks15; };
    auto WC2 = [&](int c) { float s=0.f;
        #pragma unroll
        for (int b=0;b<4;b++) s += embC[b]*w2[b*832+c]; return s*inv_ks15; };
    auto WF2 = [&](int c) { float s=0.f;
        #pragma unroll
        for (int b=0;b<4;b++) s += embF[b]*w2[b*832+c]; return s*inv_ks15; };

    float val = 0.f;
    if (gid < 192) {                       // T1c
        int i = gid / 24, o = gid % 24;
        int c = (o < 16) ? i * 16 + o : 128 + i * 8 + (o - 16);
        val = a1 * WC1(c) + a1 * sc1[i * 24 + o];
    } else if (gid < 384) {                // T1f
        int r = gid - 192; int i = r / 24, o = r % 24;
        int c = (o < 16) ? i * 16 + o : 128 + i * 8 + (o - 16);
        val = a1 * WF1(c);
    } else if (gid < 448) {                // T1v
        int r = gid - 384; int i = r / 8, jj = r % 8;
        val = a1 * s3 * WF1(192 + i * 8 + jj);
    } else if (gid < 832) {                // T2c
        int r = gid - 448; int i = r / 24, o = r % 24;
        int c = (o < 16) ? i * 16 + o : 256 + i * 8 + (o - 16);
        val = a_s * WC2(c) + 0.25f * sc2s[i * 24 + o];
    } else if (gid < 1216) {               // T2f
        int r = gid - 832; int i = r / 24, o = r % 24;
        int c = (o < 16) ? i * 16 + o : 256 + i * 8 + (o - 16);
        val = a_s * WF2(c);
    } else if (gid < 1344) {               // T2sv
        int r = gid - 1216; int i = r / 8, jj = r % 8;
        val = a_v * s3 * WF2(384 + i * 8 + jj);
    } else if (gid < 1536) {               // T2vs
        int r = gid - 1344; int u = r / 24, o = r % 24;
        int c = (o < 16) ? 576 + u * 16 + o : 704 + u * 8 + (o - 16);
        val = a_s3 * s3 * WF2(c);
    } else if (gid < 1600) {               // T2v0c
        int r = gid - 1536; int u = r / 8, jj = r % 8;
        val = a_v * WC2(512 + u * 8 + jj) + a1 * sc2v[u * 8 + jj];
    } else if (gid < 1664) {               // T2v0f
        int r = gid - 1600; int u = r / 8, jj = r % 8;
        val = a_v * WF2(512 + u * 8 + jj);
    } else {                               // T2v1
        int r = gid - 1664; int u = r / 8, jj = r % 8;
        val = a_v6 * s3 * WF2(768 + u * 8 + jj);
    }
    T[gid] = val;
}

// Load the 5 non-w taps of one channel row (c, d-, d+, h-, h+).
#define LOADRAW5(PTR, C_, DM_, DP_, HM_, HP_)                                 \
    {                                                                         \
        const float* bp = (PTR);                                              \
        C_  = bp[0];                                                          \
        DM_ = dmok ? bp[-4096] : 0.f;                                         \
        DP_ = dpok ? bp[ 4096] : 0.f;                                         \
        HM_ = hmok ? bp[  -64] : 0.f;                                         \
        HP_ = hpok ? bp[   64] : 0.f;                                         \
    }

// Features from raw taps; w+-1 come from lane shuffles (wave == w-row).
#define FEAT5(C_, DM_, DP_, HM_, HP_, S_, DD_, DH_, DW_)                      \
    {                                                                         \
        float _um = __shfl_up((C_), 1, 64);                                   \
        float _up = __shfl_down((C_), 1, 64);                                 \
        float vwm = wmok ? _um : 0.f;                                         \
        float vwp = wpok ? _up : 0.f;                                         \
        S_  = (DM_) + (DP_) + (HM_) + (HP_) + vwm + vwp;                      \
        DD_ = (DP_) - (DM_); DH_ = (HP_) - (HM_); DW_ = vwp - vwm;            \
    }

// ---------------------------------------------------------------------------
// conv1: x(8,64^3) -> ypre(48,64^3). shfl w-taps + depth-1 prefetch.
// ---------------------------------------------------------------------------
__global__ __launch_bounds__(256) void conv1_kernel(const float* __restrict__ x,
                                                    const float* __restrict__ Tg,
                                                    float* __restrict__ out,
                                                    float* __restrict__ stats) {
    __shared__ float T[448];
    __shared__ float red[4][72];
    for (int t = threadIdx.x; t < 448; t += 256) T[t] = Tg[t];
    __syncthreads();

    int idx = blockIdx.x * 256 + threadIdx.x;
    int w = idx & 63, h = (idx >> 6) & 63, d = idx >> 12;
    bool dmok = d > 0, dpok = d < 63, hmok = h > 0, hpok = h < 63,
         wmok = w > 0, wpok = w < 63;

    float acc[48];
    #pragma unroll
    for (int o = 0; o < 48; o++) acc[o] = 0.f;

    float nc, ndm, ndp, nhm, nhp;
    LOADRAW5(x + idx, nc, ndm, ndp, nhm, nhp);

    #pragma unroll 1
    for (int i = 0; i < 8; i++) {
        float c = nc, rdm = ndm, rdp = ndp, rhm = nhm, rhp = nhp;
        if (i < 7) LOADRAW5(x + (i + 1) * N3 + idx, nc, ndm, ndp, nhm, nhp);

        float S, Dd, Dh, Dw;
        FEAT5(c, rdm, rdp, rhm, rhp, S, Dd, Dh, Dw);

        const float* tc = &T[i * 24];
        const float* tf = &T[192 + i * 24];
        #pragma unroll
        for (int o = 0; o < 24; o++) acc[o] += tc[o] * c + tf[o] * S;
        const float* tv = &T[384 + i * 8];
        #pragma unroll
        for (int jj = 0; jj < 8; jj++) {
            float wv = tv[jj];
            acc[24 + jj * 3 + 0] += wv * Dd;
            acc[24 + jj * 3 + 1] += wv * Dh;
            acc[24 + jj * 3 + 2] += wv * Dw;
        }
    }
    #pragma unroll
    for (int o = 0; o < 48; o++) out[o * N3 + idx] = acc[o];

    // fused BN partial stats: q<24 -> sum(ch q); q in [24,72) -> sumsq(ch q-24)
    int lane = threadIdx.x & 63, wv = threadIdx.x >> 6;
    #pragma unroll
    for (int q = 0; q < 72; q++) {
        float val = (q < 24) ? acc[q] : acc[q - 24] * acc[q - 24];
        #pragma unroll
        for (int m = 32; m >= 1; m >>= 1) val += __shfl_xor(val, m, 64);
        if (lane == 0) red[wv][q] = val;
    }
    __syncthreads();
    if (threadIdx.x < 72) {
        float s = red[0][threadIdx.x] + red[1][threadIdx.x] +
                  red[2][threadIdx.x] + red[3][threadIdx.x];
        atomicAdd(&stats[threadIdx.x], s);
    }
}

// ---------------------------------------------------------------------------
// conv2: y(40,64^3) -> zpre(48,64^3). shfl w-taps, depth-1 prefetch on the
// scalar-row loop; vector rows keep 3-row batches (15 loads/iter ILP).
// ---------------------------------------------------------------------------
__global__ __launch_bounds__(256) void conv2_kernel(const float* __restrict__ y,
                                                    const float* __restrict__ Tg,
                                                    float* __restrict__ out,
                                                    float* __restrict__ stats) {
    __shared__ float T[1280];
    __shared__ float red[4][72];
    for (int t = threadIdx.x; t < 1280; t += 256) T[t] = Tg[448 + t];
    __syncthreads();

    int idx = blockIdx.x * 256 + threadIdx.x;
    int w = idx & 63, h = (idx >> 6) & 63, d = idx >> 12;
    bool dmok = d > 0, dpok = d < 63, hmok = h > 0, hpok = h < 63,
         wmok = w > 0, wpok = w < 63;

    float acc[48];
    #pragma unroll
    for (int o = 0; o < 48; o++) acc[o] = 0.f;

    // ---- scalar input rows (16): depth-1 prefetch ----
    {
        float nc, ndm, ndp, nhm, nhp;
        LOADRAW5(y + idx, nc, ndm, ndp, nhm, nhp);

        #pragma unroll 1
        for (int i = 0; i < 16; i++) {
            float c = nc, rdm = ndm, rdp = ndp, rhm = nhm, rhp = nhp;
            if (i < 15) LOADRAW5(y + (i + 1) * N3 + idx, nc, ndm, ndp, nhm, nhp);

            float S, Dd, Dh, Dw;
            FEAT5(c, rdm, rdp, rhm, rhp, S, Dd, Dh, Dw);

            const float* tc = &T[i * 24];
            const float* tf = &T[384 + i * 24];
            #pragma unroll
            for (int o = 0; o < 24; o++) acc[o] += tc[o] * c + tf[o] * S;
            const float* tv = &T[768 + i * 8];
            #pragma unroll
            for (int jj = 0; jj < 8; jj++) {
                float wv = tv[jj];
                acc[24 + jj * 3 + 0] += wv * Dd;
                acc[24 + jj * 3 + 1] += wv * Dh;
                acc[24 + jj * 3 + 2] += wv * Dw;
            }
        }
    }

    // ---- vector input rows: per u, 3 rows (15 loads in flight) ----
    #pragma unroll 1
    for (int u = 0; u < 8; u++) {
        float c0, r0dm, r0dp, r0hm, r0hp;
        float c1, r1dm, r1dp, r1hm, r1hp;
        float c2, r2dm, r2dp, r2hm, r2hp;
        LOADRAW5(y + (16 + u * 3 + 0) * N3 + idx, c0, r0dm, r0dp, r0hm, r0hp);
        LOADRAW5(y + (16 + u * 3 + 1) * N3 + idx, c1, r1dm, r1dp, r1hm, r1hp);
        LOADRAW5(y + (16 + u * 3 + 2) * N3 + idx, c2, r2dm, r2dp, r2hm, r2hp);

        float S0, D0_0, D0_1, D0_2;
        float S1, D1_0, D1_1, D1_2;
        float S2, D2_0, D2_1, D2_2;
        FEAT5(c0, r0dm, r0dp, r0hm, r0hp, S0, D0_0, D0_1, D0_2);
        FEAT5(c1, r1dm, r1dp, r1hm, r1hp, S1, D1_0, D1_1, D1_2);
        FEAT5(c2, r2dm, r2dp, r2hm, r2hp, S2, D2_0, D2_1, D2_2);

        // vector->scalar: T2vs[u][o] * divergence
        float Dsum = D0_0 + D1_1 + D2_2;
        const float* tvs = &T[896 + u * 24];
        #pragma unroll
        for (int o = 0; o < 24; o++) acc[o] += tvs[o] * Dsum;

        // vv0 + vv1 (Levi-Civita), all acc indices static
        const float* t0c = &T[1088 + u * 8];
        const float* t0f = &T[1152 + u * 8];
        const float* tv1 = &T[1216 + u * 8];
        #pragma unroll
        for (int jj = 0; jj < 8; jj++) {
            float kc = t0c[jj], kf = t0f[jj], k1 = tv1[jj];
            float a0 = acc[24 + jj * 3 + 0];
            float a1 = acc[24 + jj * 3 + 1];
            float a2 = acc[24 + jj * 3 + 2];
            a0 += kc * c0 + kf * S0;          // m=0 vv0
            a2 += k1 * D0_1; a1 -= k1 * D0_2; // m=0 vv1
            a1 += kc * c1 + kf * S1;          // m=1 vv0
            a0 += k1 * D1_2; a2 -= k1 * D1_0; // m=1 vv1
            a2 += kc * c2 + kf * S2;          // m=2 vv0
            a1 += k1 * D2_0; a0 -= k1 * D2_1; // m=2 vv1
            acc[24 + jj * 3 + 0] = a0;
            acc[24 + jj * 3 + 1] = a1;
            acc[24 + jj * 3 + 2] = a2;
        }
    }

    #pragma unroll
    for (int o = 0; o < 48; o++) out[o * N3 + idx] = acc[o];

    // fused BN partial stats
    int lane = threadIdx.x & 63, wv = threadIdx.x >> 6;
    #pragma unroll
    for (int q = 0; q < 72; q++) {
        float val = (q < 24) ? acc[q] : acc[q - 24] * acc[q - 24];
        #pragma unroll
        for (int mm = 32; mm >= 1; mm >>= 1) val += __shfl_xor(val, mm, 64);
        if (lane == 0) red[wv][q] = val;
    }
    __syncthreads();
    if (threadIdx.x < 72) {
        float s = red[0][threadIdx.x] + red[1][threadIdx.x] +
                  red[2][threadIdx.x] + red[3][threadIdx.x];
        atomicAdd(&stats[threadIdx.x], s);
    }
}

// ---------------------------------------------------------------------------
// BN apply + gate (finalize inlined): zp(48ch) -> out(40ch), float4/thread
// ---------------------------------------------------------------------------
__global__ __launch_bounds__(256) void bn_gate_kernel(const float* __restrict__ zp,
                                                      const float* __restrict__ stats,
                                                      const float* __restrict__ wsc,
                                                      const float* __restrict__ bsc,
                                                      const float* __restrict__ wvc,
                                                      float* __restrict__ out) {
    __shared__ float sb[56];
    if (threadIdx.x < 32) {
        int t = threadIdx.x;
        const float invN = 1.0f / 262144.0f;
        if (t < 24) {
            float mu = stats[t] * invN;
            float var = stats[24 + t] * invN - mu * mu;
            float inv = rsqrtf(var + 1e-5f);
            sb[t] = wsc[t] * inv;
            sb[24 + t] = bsc[t] - mu * wsc[t] * inv;
        } else {
            int u = t - 24;
            float s2 = stats[48 + u * 3] + stats[48 + u * 3 + 1] + stats[48 + u * 3 + 2];
            sb[48 + u] = wvc[u] * rsqrtf(s2 * invN + 1e-5f);
        }
    }
    __syncthreads();

    int idx = (blockIdx.x * 256 + threadIdx.x) * 4;
    float4 g[8];
    #pragma unroll
    for (int u = 0; u < 8; u++) {
        float4 v = *(const float4*)(zp + (16 + u) * N3 + idx);
        float sc = sb[16 + u], bi = sb[40 + u];
        g[u].x = 1.0f / (1.0f + expf(-(v.x * sc + bi)));
        g[u].y = 1.0f / (1.0f + expf(-(v.y * sc + bi)));
        g[u].z = 1.0f / (1.0f + expf(-(v.z * sc + bi)));
        g[u].w = 1.0f / (1.0f + expf(-(v.w * sc + bi)));
    }
    #pragma unroll
    for (int c = 0; c < 16; c++) {
        float4 v = *(const float4*)(zp + c * N3 + idx);
        float sc = sb[c], bi = sb[24 + c];
        float4 r;
        r.x = fmaxf(v.x * sc + bi, 0.f);
        r.y = fmaxf(v.y * sc + bi, 0.f);
        r.z = fmaxf(v.z * sc + bi, 0.f);
        r.w = fmaxf(v.w * sc + bi, 0.f);
        *(float4*)(out + c * N3 + idx) = r;
    }
    #pragma unroll
    for (int u = 0; u < 8; u++) {
        float sv = sb[48 + u];
        #pragma unroll
        for (int m = 0; m < 3; m++) {
            float4 v = *(const float4*)(zp + (24 + u * 3 + m) * N3 + idx);
            float4 r;
            r.x = v.x * sv * g[u].x;
            r.y = v.y * sv * g[u].y;
            r.z = v.z * sv * g[u].z;
            r.w = v.w * sv * g[u].w;
            *(float4*)(out + (16 + u * 3 + m) * N3 + idx) = r;
        }
    }
}

// ---------------------------------------------------------------------------
extern "C" void kernel_launch(void* const* d_in, const int* in_sizes, int n_in,
                              void* d_out, int out_size, void* d_ws, size_t ws_size,
                              hipStream_t stream) {
    const float* x      = (const float*)d_in[0];
    const float* w1     = (const float*)d_in[1];
    const float* sc1    = (const float*)d_in[2];
    const float* w2     = (const float*)d_in[3];
    const float* sc2s   = (const float*)d_in[4];
    const float* sc2v   = (const float*)d_in[5];
    const float* bn1_ws = (const float*)d_in[6];
    const float* bn1_bs = (const float*)d_in[7];
    const float* bn1_wv = (const float*)d_in[8];
    const float* bn2_ws = (const float*)d_in[9];
    const float* bn2_bs = (const float*)d_in[10];
    const float* bn2_wv = (const float*)d_in[11];
    float* out = (float*)d_out;
    char* ws = (char*)d_ws;

    float* Tg     = (float*)(ws + 0);        // 1728 floats = 6912 B
    float* stats1 = (float*)(ws + 8192);     // 72 floats
    float* stats2 = (float*)(ws + 8192 + 512);
    float* bufA   = (float*)(ws + 262144);   // 48*N3*4 = 50331648 B

    hipMemsetAsync(ws + 8192, 0, 1024, stream);
    hipLaunchKernelGGL(build_tables_kernel, dim3(7), dim3(256), 0, stream,
                       w1, sc1, w2, sc2s, sc2v, Tg);
    hipLaunchKernelGGL(conv1_kernel, dim3(1024), dim3(256), 0, stream, x, Tg, bufA, stats1);
    hipLaunchKernelGGL(bn_gate_kernel, dim3(256), dim3(256), 0, stream,
                       bufA, stats1, bn1_ws, bn1_bs, bn1_wv, out);
    hipLaunchKernelGGL(conv2_kernel, dim3(1024), dim3(256), 0, stream, out, Tg, bufA, stats2);
    hipLaunchKernelGGL(bn_gate_kernel, dim3(256), dim3(256), 0, stream,
                       bufA, stats2, bn2_ws, bn2_bs, bn2_wv, out);
}

// Round 11
// 121.393 us; speedup vs baseline: 1.5815x; 1.3002x over previous
//
#include <hip/hip_runtime.h>
#include <math.h>

#define N3 262144           // 64^3

// ===========================================================================
// Derived-feature formulation (verified R4-R10): 7-point stencil; per input
// row the conv depends only on c (center), S (sum of 6 faces), D_A (diffs).
// Lessons: R5 static acc idx; R6 row loops unroll-1; R8 no load batching via
// unroll; R9 no LDS staging; R10 shfl/prefetch alone neutral.
// R11 (this): 4 points/thread via float4 taps (1/4 VMEM instrs, 4x compute
// per iteration -> prefetch self-hides latency) + output-channel-half split
// across blockIdx.y (acc[24] float4 = 96 VGPR, no spill).
// ===========================================================================

// Table layout (floats):
// conv1 (448): T1c[8][24]@0, T1f[8][24]@192, T1v[8][8]@384
// conv2 (1280)@448: T2c[16][24]@+0, T2f[16][24]@+384, T2sv[16][8]@+768,
//   T2vs[8][24]@+896, T2v0c[8][8]@+1088, T2v0f[8][8]@+1152, T2v1[8][8]@+1216
#define TBL_TOTAL 1728

__device__ inline void lattice_emb(int p, float* embr) {
    int i = p / 9, j = (p / 3) % 3, k = p % 3;
    float gx = (float)(i - 1), gy = (float)(j - 1), gz = (float)(k - 1);
    float r = sqrtf(gx * gx + gy * gy + gz * gz);
    const float centers[4] = {0.f, 0.33333334f, 0.6666667f, 1.f};
    const float step = 0.33333334f;
    #pragma unroll
    for (int b = 0; b < 4; b++) {
        float dd = (r - centers[b]) / step;
        float e = 0.f;
        if (fabsf(dd) < 1.f)
            e = 1.14136f * expf(2.f) * expf(-1.f / fmaxf(1.f - dd * dd, 1e-9f));
        embr[b] = e;
    }
}

__global__ __launch_bounds__(256) void build_tables_kernel(
        const float* __restrict__ w1,  const float* __restrict__ sc1,
        const float* __restrict__ w2,  const float* __restrict__ sc2s,
        const float* __restrict__ sc2v, float* __restrict__ T) {
    int gid = blockIdx.x * 256 + threadIdx.x;
    if (gid >= TBL_TOTAL) return;

    const float inv_ks15 = 0.19245008972987526f;  // 1/3^1.5
    const float s3   = 1.7320508075688772f;
    const float a1   = 0.35355339059327373f;  // 1/sqrt(8)
    const float a_s  = 0.2041241452319315f;   // 1/sqrt(24)
    const float a_v  = 0.17677669529663687f;  // 1/sqrt(32)
    const float a_s3 = 0.11785113019775793f;  // a_s/sqrt(3)
    const float a_v6 = 0.07216878364870322f;  // a_v/sqrt(6)

    float embC[4], embF[4];
    lattice_emb(13, embC);   // center (r=0)
    lattice_emb(22, embF);   // face   (r=1), shared by all 6 faces

    auto WC1 = [&](int c) { float s=0.f;
        #pragma unroll
        for (int b=0;b<4;b++) s += embC[b]*w1[b*256+c]; return s*inv_ks15; };
    auto WF1 = [&](int c) { float s=0.f;
        #pragma unroll
        for (int b=0;b<4;b++) s += embF[b]*w1[b*256+c]; return s*inv_ks15; };
    auto WC2 = [&](int c) { float s=0.f;
        #pragma unroll
        for (int b=0;b<4;b++) s += embC[b]*w2[b*832+c]; return s*inv_ks15; };
    auto WF2 = [&](int c) { float s=0.f;
        #pragma unroll
        for (int b=0;b<4;b++) s += embF[b]*w2[b*832+c]; return s*inv_ks15; };

    float val = 0.f;
    if (gid < 192) {                       // T1c
        int i = gid / 24, o = gid % 24;
        int c = (o < 16) ? i * 16 + o : 128 + i * 8 + (o - 16);
        val = a1 * WC1(c) + a1 * sc1[i * 24 + o];
    } else if (gid < 384) {                // T1f
        int r = gid - 192; int i = r / 24, o = r % 24;
        int c = (o < 16) ? i * 16 + o : 128 + i * 8 + (o - 16);
        val = a1 * WF1(c);
    } else if (gid < 448) {                // T1v
        int r = gid - 384; int i = r / 8, jj = r % 8;
        val = a1 * s3 * WF1(192 + i * 8 + jj);
    } else if (gid < 832) {                // T2c
        int r = gid - 448; int i = r / 24, o = r % 24;
        int c = (o < 16) ? i * 16 + o : 256 + i * 8 + (o - 16);
        val = a_s * WC2(c) + 0.25f * sc2s[i * 24 + o];
    } else if (gid < 1216) {               // T2f
        int r = gid - 832; int i = r / 24, o = r % 24;
        int c = (o < 16) ? i * 16 + o : 256 + i * 8 + (o - 16);
        val = a_s * WF2(c);
    } else if (gid < 1344) {               // T2sv
        int r = gid - 1216; int i = r / 8, jj = r % 8;
        val = a_v * s3 * WF2(384 + i * 8 + jj);
    } else if (gid < 1536) {               // T2vs
        int r = gid - 1344; int u = r / 24, o = r % 24;
        int c = (o < 16) ? 576 + u * 16 + o : 704 + u * 8 + (o - 16);
        val = a_s3 * s3 * WF2(c);
    } else if (gid < 1600) {               // T2v0c
        int r = gid - 1536; int u = r / 8, jj = r % 8;
        val = a_v * WC2(512 + u * 8 + jj) + a1 * sc2v[u * 8 + jj];
    } else if (gid < 1664) {               // T2v0f
        int r = gid - 1600; int u = r / 8, jj = r % 8;
        val = a_v * WF2(512 + u * 8 + jj);
    } else {                               // T2v1
        int r = gid - 1664; int u = r / 8, jj = r % 8;
        val = a_v6 * s3 * WF2(768 + u * 8 + jj);
    }
    T[gid] = val;
}

// ---------------------------------------------------------------------------
// float4 helpers (explicit elementwise; no reliance on vector operators)
// ---------------------------------------------------------------------------
__device__ inline float4 f4z() { return make_float4(0.f, 0.f, 0.f, 0.f); }
__device__ inline float4 f4add(float4 a, float4 b) {
    return make_float4(a.x+b.x, a.y+b.y, a.z+b.z, a.w+b.w); }
__device__ inline float4 f4sub(float4 a, float4 b) {
    return make_float4(a.x-b.x, a.y-b.y, a.z-b.z, a.w-b.w); }
__device__ inline float4 f4fma(float s, float4 a, float4 c) {
    return make_float4(fmaf(s,a.x,c.x), fmaf(s,a.y,c.y), fmaf(s,a.z,c.z), fmaf(s,a.w,c.w)); }
__device__ inline float f4sum(float4 a) { return a.x+a.y+a.z+a.w; }
__device__ inline float f4dot(float4 a) { return a.x*a.x+a.y*a.y+a.z*a.z+a.w*a.w; }

// Load quads for c, d+-, h+- of one channel row
#define LQ5(BP, C_, DM_, DP_, HM_, HP_)                                       \
    {                                                                         \
        const float* _p = (BP);                                               \
        C_  = *(const float4*)_p;                                             \
        DM_ = dmok ? *(const float4*)(_p - 4096) : f4z();                     \
        DP_ = dpok ? *(const float4*)(_p + 4096) : f4z();                     \
        HM_ = hmok ? *(const float4*)(_p -   64) : f4z();                     \
        HP_ = hpok ? *(const float4*)(_p +   64) : f4z();                     \
    }

// w-neighbor quads from c (in-quad shifts + cross-lane shfl at quad edges)
#define WQ(C_, WM_, WP_)                                                      \
    {                                                                         \
        float _lw = __shfl_up((C_).w, 1, 64);                                 \
        float _rw = __shfl_down((C_).x, 1, 64);                               \
        WM_ = make_float4(wL ? 0.f : _lw, (C_).x, (C_).y, (C_).z);            \
        WP_ = make_float4((C_).y, (C_).z, (C_).w, wR ? 0.f : _rw);            \
    }

// ---------------------------------------------------------------------------
// conv1: x(8,64^3) -> ypre(48,64^3). 4 pts/thread, channel-half split.
// ohalf0: ch 0-23 (tc*c + tf*S); ohalf1: ch 24-47 (tv * D_axis).
// ---------------------------------------------------------------------------
__global__ __launch_bounds__(128) void conv1_kernel(const float* __restrict__ x,
                                                    const float* __restrict__ Tg,
                                                    float* __restrict__ out,
                                                    float* __restrict__ stats) {
    __shared__ float T[448];
    __shared__ float red[2][48];
    for (int t = threadIdx.x; t < 448; t += 128) T[t] = Tg[t];
    __syncthreads();

    const int ohalf = blockIdx.y;
    int idx = blockIdx.x * 512 + threadIdx.x * 4;
    int w0 = idx & 63, h = (idx >> 6) & 63, d = idx >> 12;
    bool dmok = d > 0, dpok = d < 63, hmok = h > 0, hpok = h < 63;
    bool wL = (w0 == 0), wR = (w0 == 60);

    float4 acc[24];
    #pragma unroll
    for (int o = 0; o < 24; o++) acc[o] = f4z();

    if (ohalf == 0) {
        float4 nc, ndm, ndp, nhm, nhp;
        LQ5(x + idx, nc, ndm, ndp, nhm, nhp);
        #pragma unroll 1
        for (int i = 0; i < 8; i++) {
            float4 c = nc, dmq = ndm, dpq = ndp, hmq = nhm, hpq = nhp;
            if (i < 7) LQ5(x + (i + 1) * N3 + idx, nc, ndm, ndp, nhm, nhp);
            float4 wmq, wpq; WQ(c, wmq, wpq);
            float4 S = f4add(f4add(f4add(dmq, dpq), f4add(hmq, hpq)), f4add(wmq, wpq));
            const float* tc = &T[i * 24];
            const float* tf = &T[192 + i * 24];
            #pragma unroll
            for (int o = 0; o < 24; o++)
                acc[o] = f4fma(tc[o], c, f4fma(tf[o], S, acc[o]));
        }
    } else {
        float4 nc, ndm, ndp, nhm, nhp;
        LQ5(x + idx, nc, ndm, ndp, nhm, nhp);
        #pragma unroll 1
        for (int i = 0; i < 8; i++) {
            float4 c = nc, dmq = ndm, dpq = ndp, hmq = nhm, hpq = nhp;
            if (i < 7) LQ5(x + (i + 1) * N3 + idx, nc, ndm, ndp, nhm, nhp);
            float4 wmq, wpq; WQ(c, wmq, wpq);
            float4 Dd = f4sub(dpq, dmq), Dh = f4sub(hpq, hmq), Dw = f4sub(wpq, wmq);
            const float* tv = &T[384 + i * 8];
            #pragma unroll
            for (int jj = 0; jj < 8; jj++) {
                float wv = tv[jj];
                acc[jj * 3 + 0] = f4fma(wv, Dd, acc[jj * 3 + 0]);
                acc[jj * 3 + 1] = f4fma(wv, Dh, acc[jj * 3 + 1]);
                acc[jj * 3 + 2] = f4fma(wv, Dw, acc[jj * 3 + 2]);
            }
        }
    }

    int obase = ohalf * 24;
    #pragma unroll
    for (int o = 0; o < 24; o++)
        *(float4*)(out + (obase + o) * N3 + idx) = acc[o];

    // fused BN partial stats
    int lane = threadIdx.x & 63, wvx = threadIdx.x >> 6;
    if (ohalf == 0) {
        #pragma unroll
        for (int q = 0; q < 48; q++) {
            float val = (q < 24) ? f4sum(acc[q]) : f4dot(acc[q - 24]);
            #pragma unroll
            for (int mq = 32; mq >= 1; mq >>= 1) val += __shfl_xor(val, mq, 64);
            if (lane == 0) red[wvx][q] = val;
        }
        __syncthreads();
        if (threadIdx.x < 48)
            atomicAdd(&stats[threadIdx.x], red[0][threadIdx.x] + red[1][threadIdx.x]);
    } else {
        #pragma unroll
        for (int q = 0; q < 24; q++) {
            float val = f4dot(acc[q]);
            #pragma unroll
            for (int mq = 32; mq >= 1; mq >>= 1) val += __shfl_xor(val, mq, 64);
            if (lane == 0) red[wvx][q] = val;
        }
        __syncthreads();
        if (threadIdx.x < 24)
            atomicAdd(&stats[48 + threadIdx.x], red[0][threadIdx.x] + red[1][threadIdx.x]);
    }
}

// ---------------------------------------------------------------------------
// conv2: y(40,64^3) -> zpre(48,64^3). 4 pts/thread, channel-half split.
// ohalf0: ch 0-23  = scalar rows (tc*c+tf*S) + vector rows (tvs*Dsum).
// ohalf1: ch 24-47 = scalar rows (tv*D) + vector rows (vv0 + vv1 Levi-Civita).
// ---------------------------------------------------------------------------
__global__ __launch_bounds__(128) void conv2_kernel(const float* __restrict__ y,
                                                    const float* __restrict__ Tg,
                                                    float* __restrict__ out,
                                                    float* __restrict__ stats) {
    __shared__ float T[1280];
    __shared__ float red[2][48];
    for (int t = threadIdx.x; t < 1280; t += 128) T[t] = Tg[448 + t];
    __syncthreads();

    const int ohalf = blockIdx.y;
    int idx = blockIdx.x * 512 + threadIdx.x * 4;
    int w0 = idx & 63, h = (idx >> 6) & 63, d = idx >> 12;
    bool dmok = d > 0, dpok = d < 63, hmok = h > 0, hpok = h < 63;
    bool wL = (w0 == 0), wR = (w0 == 60);

    float4 acc[24];
    #pragma unroll
    for (int o = 0; o < 24; o++) acc[o] = f4z();

    if (ohalf == 0) {
        // ---- scalar rows: c,S -> tc/tf ----
        float4 nc, ndm, ndp, nhm, nhp;
        LQ5(y + idx, nc, ndm, ndp, nhm, nhp);
        #pragma unroll 1
        for (int i = 0; i < 16; i++) {
            float4 c = nc, dmq = ndm, dpq = ndp, hmq = nhm, hpq = nhp;
            if (i < 15) LQ5(y + (i + 1) * N3 + idx, nc, ndm, ndp, nhm, nhp);
            float4 wmq, wpq; WQ(c, wmq, wpq);
            float4 S = f4add(f4add(f4add(dmq, dpq), f4add(hmq, hpq)), f4add(wmq, wpq));
            const float* tc = &T[i * 24];
            const float* tf = &T[384 + i * 24];
            #pragma unroll
            for (int o = 0; o < 24; o++)
                acc[o] = f4fma(tc[o], c, f4fma(tf[o], S, acc[o]));
        }
        // ---- vector rows: only Dsum needed (divergence) ----
        #pragma unroll 1
        for (int u = 0; u < 8; u++) {
            const float* b0 = y + (16 + u * 3 + 0) * N3 + idx;
            const float* b1 = b0 + N3;
            const float* b2 = b1 + N3;
            float4 qdm = dmok ? *(const float4*)(b0 - 4096) : f4z();
            float4 qdp = dpok ? *(const float4*)(b0 + 4096) : f4z();
            float4 qhm = hmok ? *(const float4*)(b1 -   64) : f4z();
            float4 qhp = hpok ? *(const float4*)(b1 +   64) : f4z();
            float4 c2  = *(const float4*)b2;
            float4 wmq, wpq; WQ(c2, wmq, wpq);
            float4 Dsum = f4add(f4add(f4sub(qdp, qdm), f4sub(qhp, qhm)), f4sub(wpq, wmq));
            const float* tvs = &T[896 + u * 24];
            #pragma unroll
            for (int o = 0; o < 24; o++)
                acc[o] = f4fma(tvs[o], Dsum, acc[o]);
        }
    } else {
        // ---- scalar rows: D only -> T2sv ----
        float4 nc, ndm, ndp, nhm, nhp;
        LQ5(y + idx, nc, ndm, ndp, nhm, nhp);
        #pragma unroll 1
        for (int i = 0; i < 16; i++) {
            float4 c = nc, dmq = ndm, dpq = ndp, hmq = nhm, hpq = nhp;
            if (i < 15) LQ5(y + (i + 1) * N3 + idx, nc, ndm, ndp, nhm, nhp);
            float4 wmq, wpq; WQ(c, wmq, wpq);
            float4 Dd = f4sub(dpq, dmq), Dh = f4sub(hpq, hmq), Dw = f4sub(wpq, wmq);
            const float* tv = &T[768 + i * 8];
            #pragma unroll
            for (int jj = 0; jj < 8; jj++) {
                float wv = tv[jj];
                acc[jj * 3 + 0] = f4fma(wv, Dd, acc[jj * 3 + 0]);
                acc[jj * 3 + 1] = f4fma(wv, Dh, acc[jj * 3 + 1]);
                acc[jj * 3 + 2] = f4fma(wv, Dw, acc[jj * 3 + 2]);
            }
        }
        // ---- vector rows: vv0 + vv1, 3 explicit m-blocks per u ----
        #pragma unroll 1
        for (int u = 0; u < 8; u++) {
            const float* t0c = &T[1088 + u * 8];
            const float* t0f = &T[1152 + u * 8];
            const float* tv1 = &T[1216 + u * 8];
            {   // m=0: vv0 -> comp0; +k1*Dh -> comp2; -k1*Dw -> comp1
                float4 c, dmq, dpq, hmq, hpq;
                LQ5(y + (16 + u * 3 + 0) * N3 + idx, c, dmq, dpq, hmq, hpq);
                float4 wmq, wpq; WQ(c, wmq, wpq);
                float4 S = f4add(f4add(f4add(dmq, dpq), f4add(hmq, hpq)), f4add(wmq, wpq));
                float4 Dh = f4sub(hpq, hmq), Dw = f4sub(wpq, wmq);
                #pragma unroll
                for (int jj = 0; jj < 8; jj++) {
                    float k1 = tv1[jj];
                    acc[jj * 3 + 0] = f4fma(t0c[jj], c, f4fma(t0f[jj], S, acc[jj * 3 + 0]));
                    acc[jj * 3 + 2] = f4fma(k1, Dh, acc[jj * 3 + 2]);
                    acc[jj * 3 + 1] = f4fma(-k1, Dw, acc[jj * 3 + 1]);
                }
            }
            {   // m=1: vv0 -> comp1; +k1*Dw -> comp0; -k1*Dd -> comp2
                float4 c, dmq, dpq, hmq, hpq;
                LQ5(y + (16 + u * 3 + 1) * N3 + idx, c, dmq, dpq, hmq, hpq);
                float4 wmq, wpq; WQ(c, wmq, wpq);
                float4 S = f4add(f4add(f4add(dmq, dpq), f4add(hmq, hpq)), f4add(wmq, wpq));
                float4 Dd = f4sub(dpq, dmq), Dw = f4sub(wpq, wmq);
                #pragma unroll
                for (int jj = 0; jj < 8; jj++) {
                    float k1 = tv1[jj];
                    acc[jj * 3 + 1] = f4fma(t0c[jj], c, f4fma(t0f[jj], S, acc[jj * 3 + 1]));
                    acc[jj * 3 + 0] = f4fma(k1, Dw, acc[jj * 3 + 0]);
                    acc[jj * 3 + 2] = f4fma(-k1, Dd, acc[jj * 3 + 2]);
                }
            }
            {   // m=2: vv0 -> comp2; +k1*Dd -> comp1; -k1*Dh -> comp0
                float4 c, dmq, dpq, hmq, hpq;
                LQ5(y + (16 + u * 3 + 2) * N3 + idx, c, dmq, dpq, hmq, hpq);
                float4 wmq, wpq; WQ(c, wmq, wpq);
                float4 S = f4add(f4add(f4add(dmq, dpq), f4add(hmq, hpq)), f4add(wmq, wpq));
                float4 Dd = f4sub(dpq, dmq), Dh = f4sub(hpq, hmq);
                #pragma unroll
                for (int jj = 0; jj < 8; jj++) {
                    float k1 = tv1[jj];
                    acc[jj * 3 + 2] = f4fma(t0c[jj], c, f4fma(t0f[jj], S, acc[jj * 3 + 2]));
                    acc[jj * 3 + 1] = f4fma(k1, Dd, acc[jj * 3 + 1]);
                    acc[jj * 3 + 0] = f4fma(-k1, Dh, acc[jj * 3 + 0]);
                }
            }
        }
    }

    int obase = ohalf * 24;
    #pragma unroll
    for (int o = 0; o < 24; o++)
        *(float4*)(out + (obase + o) * N3 + idx) = acc[o];

    // fused BN partial stats
    int lane = threadIdx.x & 63, wvx = threadIdx.x >> 6;
    if (ohalf == 0) {
        #pragma unroll
        for (int q = 0; q < 48; q++) {
            float val = (q < 24) ? f4sum(acc[q]) : f4dot(acc[q - 24]);
            #pragma unroll
            for (int mq = 32; mq >= 1; mq >>= 1) val += __shfl_xor(val, mq, 64);
            if (lane == 0) red[wvx][q] = val;
        }
        __syncthreads();
        if (threadIdx.x < 48)
            atomicAdd(&stats[threadIdx.x], red[0][threadIdx.x] + red[1][threadIdx.x]);
    } else {
        #pragma unroll
        for (int q = 0; q < 24; q++) {
            float val = f4dot(acc[q]);
            #pragma unroll
            for (int mq = 32; mq >= 1; mq >>= 1) val += __shfl_xor(val, mq, 64);
            if (lane == 0) red[wvx][q] = val;
        }
        __syncthreads();
        if (threadIdx.x < 24)
            atomicAdd(&stats[48 + threadIdx.x], red[0][threadIdx.x] + red[1][threadIdx.x]);
    }
}

// ---------------------------------------------------------------------------
// BN apply + gate (finalize inlined): zp(48ch) -> out(40ch), float4/thread
// ---------------------------------------------------------------------------
__global__ __launch_bounds__(128) void bn_gate_kernel(const float* __restrict__ zp,
                                                      const float* __restrict__ stats,
                                                      const float* __restrict__ wsc,
                                                      const float* __restrict__ bsc,
                                                      const float* __restrict__ wvc,
                                                      float* __restrict__ out) {
    __shared__ float sb[56];
    if (threadIdx.x < 32) {
        int t = threadIdx.x;
        const float invN = 1.0f / 262144.0f;
        if (t < 24) {
            float mu = stats[t] * invN;
            float var = stats[24 + t] * invN - mu * mu;
            float inv = rsqrtf(var + 1e-5f);
            sb[t] = wsc[t] * inv;
            sb[24 + t] = bsc[t] - mu * wsc[t] * inv;
        } else {
            int u = t - 24;
            float s2 = stats[48 + u * 3] + stats[48 + u * 3 + 1] + stats[48 + u * 3 + 2];
            sb[48 + u] = wvc[u] * rsqrtf(s2 * invN + 1e-5f);
        }
    }
    __syncthreads();

    int idx = (blockIdx.x * 128 + threadIdx.x) * 4;
    float4 g[8];
    #pragma unroll
    for (int u = 0; u < 8; u++) {
        float4 v = *(const float4*)(zp + (16 + u) * N3 + idx);
        float sc = sb[16 + u], bi = sb[40 + u];
        g[u].x = 1.0f / (1.0f + expf(-(v.x * sc + bi)));
        g[u].y = 1.0f / (1.0f + expf(-(v.y * sc + bi)));
        g[u].z = 1.0f / (1.0f + expf(-(v.z * sc + bi)));
        g[u].w = 1.0f / (1.0f + expf(-(v.w * sc + bi)));
    }
    #pragma unroll
    for (int c = 0; c < 16; c++) {
        float4 v = *(const float4*)(zp + c * N3 + idx);
        float sc = sb[c], bi = sb[24 + c];
        float4 r;
        r.x = fmaxf(v.x * sc + bi, 0.f);
        r.y = fmaxf(v.y * sc + bi, 0.f);
        r.z = fmaxf(v.z * sc + bi, 0.f);
        r.w = fmaxf(v.w * sc + bi, 0.f);
        *(float4*)(out + c * N3 + idx) = r;
    }
    #pragma unroll
    for (int u = 0; u < 8; u++) {
        float sv = sb[48 + u];
        #pragma unroll
        for (int m = 0; m < 3; m++) {
            float4 v = *(const float4*)(zp + (24 + u * 3 + m) * N3 + idx);
            float4 r;
            r.x = v.x * sv * g[u].x;
            r.y = v.y * sv * g[u].y;
            r.z = v.z * sv * g[u].z;
            r.w = v.w * sv * g[u].w;
            *(float4*)(out + (16 + u * 3 + m) * N3 + idx) = r;
        }
    }
}

// ---------------------------------------------------------------------------
extern "C" void kernel_launch(void* const* d_in, const int* in_sizes, int n_in,
                              void* d_out, int out_size, void* d_ws, size_t ws_size,
                              hipStream_t stream) {
    const float* x      = (const float*)d_in[0];
    const float* w1     = (const float*)d_in[1];
    const float* sc1    = (const float*)d_in[2];
    const float* w2     = (const float*)d_in[3];
    const float* sc2s   = (const float*)d_in[4];
    const float* sc2v   = (const float*)d_in[5];
    const float* bn1_ws = (const float*)d_in[6];
    const float* bn1_bs = (const float*)d_in[7];
    const float* bn1_wv = (const float*)d_in[8];
    const float* bn2_ws = (const float*)d_in[9];
    const float* bn2_bs = (const float*)d_in[10];
    const float* bn2_wv = (const float*)d_in[11];
    float* out = (float*)d_out;
    char* ws = (char*)d_ws;

    float* Tg     = (float*)(ws + 0);        // 1728 floats = 6912 B
    float* stats1 = (float*)(ws + 8192);     // 72 floats
    float* stats2 = (float*)(ws + 8192 + 512);
    float* bufA   = (float*)(ws + 262144);   // 48*N3*4 = 50331648 B

    hipMemsetAsync(ws + 8192, 0, 1024, stream);
    hipLaunchKernelGGL(build_tables_kernel, dim3(7), dim3(256), 0, stream,
                       w1, sc1, w2, sc2s, sc2v, Tg);
    hipLaunchKernelGGL(conv1_kernel, dim3(512, 2), dim3(128), 0, stream, x, Tg, bufA, stats1);
    hipLaunchKernelGGL(bn_gate_kernel, dim3(512), dim3(128), 0, stream,
                       bufA, stats1, bn1_ws, bn1_bs, bn1_wv, out);
    hipLaunchKernelGGL(conv2_kernel, dim3(512, 2), dim3(128), 0, stream, out, Tg, bufA, stats2);
    hipLaunchKernelGGL(bn_gate_kernel, dim3(512), dim3(128), 0, stream,
                       bufA, stats2, bn2_ws, bn2_bs, bn2_wv, out);
}